// Round 5
// baseline (140.727 us; speedup 1.0000x reference)
//
#include <hip/hip_runtime.h>
#include <stdint.h>

// B=8, Q=2048, D=256, H=8, L=3, P=4, HD=32
// vproj rows: level-major, T={2048,1024,512}, LOFF={0,16384,24576}, total 28672

typedef __attribute__((ext_vector_type(8))) short bf16x8;
typedef __attribute__((ext_vector_type(8))) unsigned short u16x8;
typedef __attribute__((ext_vector_type(4))) float f32x4;

__device__ __forceinline__ unsigned short f2bf(float f) {
    union { float f; uint32_t u; } v; v.f = f;
    return (unsigned short)((v.u + 0x7FFFu + ((v.u >> 16) & 1u)) >> 16);  // RNE
}
__device__ __forceinline__ float bf2f(unsigned short u) {
    union { uint32_t u; float f; } v; v.u = ((uint32_t)u) << 16;
    return v.f;
}

// ---------------------------------------------------------------------------
// K0: pre-swizzle all weights to bf16 in the GEMM staging layout
// [k0t][slot][col][kk]  (k = k0t*32 + slot*8 + kk), so B-staging = memcpy.
//  seg0: Wcat = [Woff|Waw]  192 cols   (ids 0..49151)
//  seg1: Wv cols 0..127     128 cols   (ids 49152..81919)
//  seg2: Wo                 256 cols   (ids 81920..147455)
// Plus bcat[192] = [boff|baw] f32.
// ---------------------------------------------------------------------------
__global__ __launch_bounds__(256) void swizzle_w_kernel(
    const float* __restrict__ Woff, const float* __restrict__ Waw,
    const float* __restrict__ boff, const float* __restrict__ baw,
    const float* __restrict__ Wv, const float* __restrict__ Wo,
    unsigned short* __restrict__ wcat, unsigned short* __restrict__ wvs,
    unsigned short* __restrict__ wos, float* __restrict__ bcat)
{
    const int id = blockIdx.x * 256 + threadIdx.x;   // 0..147455
    float v; unsigned short* dst;
    if (id < 49152) {
        const int rel = id;
        const int kk = rel & 7, c2 = rel >> 3;
        const int col = c2 % 192, sb = c2 / 192;
        const int k = (sb >> 2) * 32 + (sb & 3) * 8 + kk;
        v = (col < 96) ? Woff[k * 96 + col] : Waw[k * 96 + (col - 96)];
        dst = wcat + rel;
    } else if (id < 81920) {
        const int rel = id - 49152;
        const int kk = rel & 7, c2 = rel >> 3;
        const int col = c2 & 127, sb = c2 >> 7;
        const int k = (sb >> 2) * 32 + (sb & 3) * 8 + kk;
        v = Wv[k * 256 + col];
        dst = wvs + rel;
    } else {
        const int rel = id - 81920;
        const int kk = rel & 7, c2 = rel >> 3;
        const int col = c2 & 255, sb = c2 >> 8;
        const int k = (sb >> 2) * 32 + (sb & 3) * 8 + kk;
        v = Wo[k * 256 + col];
        dst = wos + rel;
    }
    *dst = f2bf(v);
    if (id < 192) bcat[id] = (id < 96) ? boff[id] : baw[id - 96];
}

// ---------------------------------------------------------------------------
// K1: fused value projections. vproj[row][0..127] bf16 = (value @ Wv + bv).
// Tile 128x128, BK=32, 4 waves 2x2 (wave 64x64), B from pre-swizzled wvs.
// ---------------------------------------------------------------------------
__global__ __launch_bounds__(256) void vproj_kernel(
    const float* __restrict__ v0, const float* __restrict__ v1,
    const float* __restrict__ v2,
    const unsigned short* __restrict__ wvs, const float* __restrict__ bv,
    unsigned short* __restrict__ vproj)
{
    __shared__ unsigned short Asub[4][128][8];  // 8 KB
    __shared__ unsigned short Bsub[4][128][8];  // 8 KB
    __shared__ float Epi2[32][132];             // 16.5 KB

    const int t = threadIdx.x;
    const int row0 = blockIdx.x * 128;

    const float* Ap; int arow;
    if (row0 < 16384)      { Ap = v0; arow = row0; }
    else if (row0 < 24576) { Ap = v1; arow = row0 - 16384; }
    else                   { Ap = v2; arow = row0 - 24576; }

    const int ar = t >> 1, ah = t & 1;
    const int w = t >> 6, lane = t & 63;
    const int wr = w >> 1, wc = w & 1;
    const int fr = lane & 15, sl = lane >> 4;

    f32x4 acc[4][4];
#pragma unroll
    for (int m = 0; m < 4; ++m)
#pragma unroll
        for (int n = 0; n < 4; ++n) acc[m][n] = (f32x4){0.f, 0.f, 0.f, 0.f};

    for (int k0t = 0; k0t < 8; ++k0t) {
        const int k0 = k0t * 32;
#pragma unroll
        for (int q = 0; q < 2; ++q) {           // stage A (f32 -> bf16)
            const int slot = ah * 2 + q;
            const float* src = &Ap[(size_t)(arow + ar) * 256 + k0 + slot * 8];
            const float4 f0 = *reinterpret_cast<const float4*>(src);
            const float4 f1 = *reinterpret_cast<const float4*>(src + 4);
            u16x8 pk;
            pk[0]=f2bf(f0.x); pk[1]=f2bf(f0.y); pk[2]=f2bf(f0.z); pk[3]=f2bf(f0.w);
            pk[4]=f2bf(f1.x); pk[5]=f2bf(f1.y); pk[6]=f2bf(f1.z); pk[7]=f2bf(f1.w);
            *reinterpret_cast<u16x8*>(&Asub[slot][ar][0]) = pk;
        }
        {                                        // stage B: pure 16B copies
            const u16x8* src = reinterpret_cast<const u16x8*>(wvs + (size_t)k0t * 4096);
#pragma unroll
            for (int i = 0; i < 2; ++i) {
                const int ch = t + i * 256;      // 0..511
                *reinterpret_cast<u16x8*>(&Bsub[ch >> 7][ch & 127][0]) = src[ch];
            }
        }
        __syncthreads();

        bf16x8 bfrag[4];
#pragma unroll
        for (int n = 0; n < 4; ++n)
            bfrag[n] = *reinterpret_cast<bf16x8*>(&Bsub[sl][wc * 64 + n * 16 + fr][0]);
#pragma unroll
        for (int m = 0; m < 4; ++m) {
            bf16x8 afrag = *reinterpret_cast<bf16x8*>(&Asub[sl][wr * 64 + m * 16 + fr][0]);
#pragma unroll
            for (int n = 0; n < 4; ++n)
                acc[m][n] = __builtin_amdgcn_mfma_f32_16x16x32_bf16(afrag, bfrag[n], acc[m][n], 0, 0, 0);
        }
        __syncthreads();
    }

    float bs[4];
#pragma unroll
    for (int n = 0; n < 4; ++n) bs[n] = bv[wc * 64 + n * 16 + fr];

#pragma unroll
    for (int m = 0; m < 4; ++m) {
#pragma unroll
        for (int n = 0; n < 4; ++n)
#pragma unroll
            for (int j = 0; j < 4; ++j)
                Epi2[wr * 16 + sl * 4 + j][wc * 64 + n * 16 + fr] = acc[m][n][j] + bs[n];
        __syncthreads();
#pragma unroll
        for (int i = 0; i < 2; ++i) {            // 512 short8 chunks, 2/thread
            const int idx = t + i * 256;
            const int rb = idx >> 4, c8 = idx & 15;
            const int grow = row0 + m * 16 + (rb >> 4) * 64 + (rb & 15);
            u16x8 pk;
#pragma unroll
            for (int e = 0; e < 8; ++e) pk[e] = f2bf(Epi2[rb][c8 * 8 + e]);
            *reinterpret_cast<u16x8*>(&vproj[(size_t)grow * 128 + c8 * 8]) = pk;
        }
        __syncthreads();
    }
}

// ---------------------------------------------------------------------------
// MEGA: per 64-query tile: logits GEMM -> in-LDS softmax+sidx -> sampling
// (gather from vproj, XCD-affine batch) -> output GEMM -> coalesced stores.
// Grid 256; bid&7 = batch (matches XCD round-robin for L2 locality).
// ---------------------------------------------------------------------------
__global__ __launch_bounds__(256) void mega_kernel(
    const float* __restrict__ query,           // [16384,256]
    const float* __restrict__ refp,            // [16384]
    const unsigned short* __restrict__ wcat,   // pre-swizzled [8][4][192][8]
    const float* __restrict__ bcat,            // [192]
    const unsigned short* __restrict__ vproj,  // [28672,128] bf16
    const unsigned short* __restrict__ wos,    // pre-swizzled [8][4][256][8]
    const float* __restrict__ bo,              // [256]
    float* __restrict__ out)                   // [16384,256]
{
    __shared__ __align__(16) unsigned short SM0[8192];  // 16 KB: A/B stage | Bsub2
    __shared__ float Epi[64][196];                      // 50.2 KB
    __shared__ unsigned short omid[32][66][8];          // 33.8 KB (66: bank-spread pad)

    unsigned short (*Asub)[64][8]  = reinterpret_cast<unsigned short(*)[64][8]>(SM0);          // [4][64][8]
    unsigned short (*Bsub)[192][8] = reinterpret_cast<unsigned short(*)[192][8]>(SM0 + 2048);  // [4][192][8]
    unsigned short (*Bsub2)[256][8]= reinterpret_cast<unsigned short(*)[256][8]>(SM0);         // [4][256][8]

    const int t = threadIdx.x;
    const int bid = blockIdx.x;
    const int b = bid & 7;
    const int q0 = b * 2048 + (bid >> 3) * 64;

    const int w = t >> 6, lane = t & 63;
    const int fr = lane & 15, sl = lane >> 4;

    // ---- Phase A: logits GEMM (64 x 192, K=256) ----
    {
        const int wr = w >> 1, wc = w & 1;      // wave: 32 rows x 96 cols
        f32x4 accA[2][6];
#pragma unroll
        for (int m = 0; m < 2; ++m)
#pragma unroll
            for (int n = 0; n < 6; ++n) accA[m][n] = (f32x4){0.f, 0.f, 0.f, 0.f};

        const int ar = t >> 2, as = t & 3;
        for (int k0t = 0; k0t < 8; ++k0t) {
            const int k0 = k0t * 32;
            {
                const float* src = &query[(size_t)(q0 + ar) * 256 + k0 + as * 8];
                const float4 f0 = *reinterpret_cast<const float4*>(src);
                const float4 f1 = *reinterpret_cast<const float4*>(src + 4);
                u16x8 pk;
                pk[0]=f2bf(f0.x); pk[1]=f2bf(f0.y); pk[2]=f2bf(f0.z); pk[3]=f2bf(f0.w);
                pk[4]=f2bf(f1.x); pk[5]=f2bf(f1.y); pk[6]=f2bf(f1.z); pk[7]=f2bf(f1.w);
                *reinterpret_cast<u16x8*>(&Asub[as][ar][0]) = pk;
            }
            {
                const u16x8* src = reinterpret_cast<const u16x8*>(wcat + (size_t)k0t * 6144);
#pragma unroll
                for (int i = 0; i < 3; ++i) {
                    const int ch = t + i * 256;  // 0..767
                    *reinterpret_cast<u16x8*>(&Bsub[ch / 192][ch % 192][0]) = src[ch];
                }
            }
            __syncthreads();
            bf16x8 bfrag[6];
#pragma unroll
            for (int n = 0; n < 6; ++n)
                bfrag[n] = *reinterpret_cast<bf16x8*>(&Bsub[sl][wc * 96 + n * 16 + fr][0]);
#pragma unroll
            for (int m = 0; m < 2; ++m) {
                bf16x8 afrag = *reinterpret_cast<bf16x8*>(&Asub[sl][wr * 32 + m * 16 + fr][0]);
#pragma unroll
                for (int n = 0; n < 6; ++n)
                    accA[m][n] = __builtin_amdgcn_mfma_f32_16x16x32_bf16(afrag, bfrag[n], accA[m][n], 0, 0, 0);
            }
            __syncthreads();
        }
        // logits + bias -> Epi
#pragma unroll
        for (int n = 0; n < 6; ++n) {
            const int col = (w & 1) * 96 + n * 16 + fr;
            const float bsn = bcat[col];
#pragma unroll
            for (int m = 0; m < 2; ++m)
#pragma unroll
                for (int j = 0; j < 4; ++j)
                    Epi[wr * 32 + m * 16 + sl * 4 + j][col] = accA[m][n][j] + bsn;
        }
    }
    __syncthreads();

    // ---- softmax (cols 96..191) + sidx (cols 0..95), in place ----
#pragma unroll
    for (int i = 0; i < 2; ++i) {
        const int p = t + i * 256;
        const int q = p >> 3, h = p & 7;
        const float ref = refp[q0 + q];
        float* lg = &Epi[q][96 + h * 12];
        float mx = -1e30f;
#pragma unroll
        for (int jj = 0; jj < 12; ++jj) mx = fmaxf(mx, lg[jj]);
        float e[12]; float s = 0.f;
#pragma unroll
        for (int jj = 0; jj < 12; ++jj) { e[jj] = expf(lg[jj] - mx); s += e[jj]; }
        const float inv = 1.f / s;
#pragma unroll
        for (int jj = 0; jj < 12; ++jj) lg[jj] = e[jj] * inv;
        float* off = &Epi[q][h * 12];
#pragma unroll
        for (int jj = 0; jj < 12; ++jj) {
            const int l = jj >> 2;
            const int T = 2048 >> l;
            float pos = ref + off[jj] / (float)T;
            pos = fminf(fmaxf(pos, 0.f), 1.f);
            off[jj] = pos * (float)(T - 1);
        }
    }
    __syncthreads();

    // ---- Phase B: sampling -> omid tile (bf16, staging layout) ----
    {
        const int sh = t >> 5, sc = t & 31;
        const int so = t >> 3, se = t & 7;       // omid write coords
#pragma unroll 2
        for (int qq = 0; qq < 64; ++qq) {
            float acc = 0.f;
#pragma unroll
            for (int l = 0; l < 3; ++l) {
                const int T = 2048 >> l;
                const int loff = (l == 0) ? 0 : ((l == 1) ? 16384 : 24576);
#pragma unroll
                for (int p = 0; p < 4; ++p) {
                    const int j = sh * 12 + l * 4 + p;
                    const float wgt  = Epi[qq][96 + j];
                    const float sidx = Epi[qq][j];
                    int ifl = (int)sidx;
                    ifl = min(max(ifl, 0), T - 2);
                    const float wce = sidx - (float)ifl;
                    const size_t base = ((size_t)(loff + b * T + ifl)) * 128 + p * 32 + sc;
                    const float vf = bf2f(vproj[base]);
                    const float vc = bf2f(vproj[base + 128]);
                    acc += wgt * (vf + wce * (vc - vf));
                }
            }
            omid[so][qq][se] = f2bf(acc);
        }
    }
    __syncthreads();

    // ---- Phase C: output GEMM (64 x 256, K=256), A = omid (LDS) ----
    f32x4 accC[4][4];
#pragma unroll
    for (int m = 0; m < 4; ++m)
#pragma unroll
        for (int n = 0; n < 4; ++n) accC[m][n] = (f32x4){0.f, 0.f, 0.f, 0.f};

    for (int k0t = 0; k0t < 8; ++k0t) {
        {
            const u16x8* src = reinterpret_cast<const u16x8*>(wos + (size_t)k0t * 8192);
#pragma unroll
            for (int i = 0; i < 4; ++i) {
                const int ch = t + i * 256;      // 0..1023
                *reinterpret_cast<u16x8*>(&Bsub2[ch >> 8][ch & 255][0]) = src[ch];
            }
        }
        __syncthreads();
        bf16x8 bfragC[4];
#pragma unroll
        for (int n = 0; n < 4; ++n)
            bfragC[n] = *reinterpret_cast<bf16x8*>(&Bsub2[sl][w * 64 + n * 16 + fr][0]);
#pragma unroll
        for (int m = 0; m < 4; ++m) {
            bf16x8 afrag = *reinterpret_cast<bf16x8*>(&omid[k0t * 4 + sl][m * 16 + fr][0]);
#pragma unroll
            for (int n = 0; n < 4; ++n)
                accC[m][n] = __builtin_amdgcn_mfma_f32_16x16x32_bf16(afrag, bfragC[n], accC[m][n], 0, 0, 0);
        }
        __syncthreads();
    }

    // ---- Epilogue: stage 128-col halves through Epi region, store f32 ----
    float (*OutS)[132] = reinterpret_cast<float(*)[132]>(&Epi[0][0]);  // 64x132 f32
#pragma unroll
    for (int hh = 0; hh < 2; ++hh) {
        if ((w >> 1) == hh) {
            const int wl = w & 1;
#pragma unroll
            for (int n = 0; n < 4; ++n) {
                const int cl = wl * 64 + n * 16 + fr;
                const float bsn = bo[hh * 128 + cl];
#pragma unroll
                for (int m = 0; m < 4; ++m)
#pragma unroll
                    for (int j = 0; j < 4; ++j)
                        OutS[m * 16 + sl * 4 + j][cl] = accC[m][n][j] + bsn;
            }
        }
        __syncthreads();
#pragma unroll
        for (int i = 0; i < 8; ++i) {            // 2048 float4, 8/thread
            const int idx = t + i * 256;
            const int r = idx >> 5, c4 = idx & 31;
            const float4 o = *reinterpret_cast<const float4*>(&OutS[r][c4 * 4]);
            *reinterpret_cast<float4*>(&out[(size_t)(q0 + r) * 256 + hh * 128 + c4 * 4]) = o;
        }
        __syncthreads();
    }
}

extern "C" void kernel_launch(void* const* d_in, const int* in_sizes, int n_in,
                              void* d_out, int out_size, void* d_ws, size_t ws_size,
                              hipStream_t stream) {
    (void)in_sizes; (void)n_in; (void)out_size; (void)ws_size;
    const float* query = (const float*)d_in[0];
    const float* refp  = (const float*)d_in[1];
    const float* v0    = (const float*)d_in[2];
    const float* v1    = (const float*)d_in[3];
    const float* v2    = (const float*)d_in[4];
    const float* Woff  = (const float*)d_in[5];
    const float* boff  = (const float*)d_in[6];
    const float* Waw   = (const float*)d_in[7];
    const float* baw   = (const float*)d_in[8];
    const float* Wv    = (const float*)d_in[9];
    const float* bv    = (const float*)d_in[10];
    const float* Wo    = (const float*)d_in[11];
    const float* bo    = (const float*)d_in[12];
    float* out = (float*)d_out;

    char* ws = (char*)d_ws;
    unsigned short* vproj = (unsigned short*)(ws);            // 7,340,032 B
    unsigned short* wcat  = (unsigned short*)(ws + 7340032);  //    98,304 B
    unsigned short* wvs   = (unsigned short*)(ws + 7438336);  //    65,536 B
    unsigned short* wos   = (unsigned short*)(ws + 7503872);  //   131,072 B
    float*          bcat  = (float*)(ws + 7634944);           //       768 B

    // K0: weight pre-swizzle (bf16, staging layout)
    swizzle_w_kernel<<<576, 256, 0, stream>>>(Woff, Waw, boff, baw, Wv, Wo,
                                              wcat, wvs, wos, bcat);

    // K1: fused value projections (3 levels, only Wv cols 0..127 consumed)
    vproj_kernel<<<224, 256, 0, stream>>>(v0, v1, v2, wvs, bv, vproj);

    // K2: mega (logits GEMM + softmax + sample + output GEMM)
    mega_kernel<<<256, 256, 0, stream>>>(query, refp, wcat, bcat, vproj, wos, bo, out);
}

// Round 6
// 60.007 us; speedup vs baseline: 2.3452x; 2.3452x over previous
//
#include <hip/hip_runtime.h>
#include <stdint.h>

// B=8, Q=2048, D=256, H=8, L=3, P=4, HD=32
// vproj rows: level-major, T={2048,1024,512}, LOFF={0,16384,24576}, total 28672

typedef __attribute__((ext_vector_type(8))) short bf16x8;
typedef __attribute__((ext_vector_type(8))) unsigned short u16x8;
typedef __attribute__((ext_vector_type(4))) float f32x4;

__device__ __forceinline__ unsigned short f2bf(float f) {
    union { float f; uint32_t u; } v; v.f = f;
    return (unsigned short)((v.u + 0x7FFFu + ((v.u >> 16) & 1u)) >> 16);  // RNE
}
__device__ __forceinline__ float bf2f(unsigned short u) {
    union { uint32_t u; float f; } v; v.u = ((uint32_t)u) << 16;
    return v.f;
}

// ---------------------------------------------------------------------------
// K0: pre-swizzle all weights to bf16 in the GEMM staging layout
// [k0t][slot][col][kk]  (k = k0t*32 + slot*8 + kk), so B-staging = memcpy.
//  seg0: Wcat = [Woff|Waw]  192 cols   (ids 0..49151)
//  seg1: Wv cols 0..127     128 cols   (ids 49152..81919)
//  seg2: Wo                 256 cols   (ids 81920..147455)
// Plus bcat[192] = [boff|baw] f32.
// ---------------------------------------------------------------------------
__global__ __launch_bounds__(256) void swizzle_w_kernel(
    const float* __restrict__ Woff, const float* __restrict__ Waw,
    const float* __restrict__ boff, const float* __restrict__ baw,
    const float* __restrict__ Wv, const float* __restrict__ Wo,
    unsigned short* __restrict__ wcat, unsigned short* __restrict__ wvs,
    unsigned short* __restrict__ wos, float* __restrict__ bcat)
{
    const int id = blockIdx.x * 256 + threadIdx.x;   // 0..147455
    float v; unsigned short* dst;
    if (id < 49152) {
        const int rel = id;
        const int kk = rel & 7, c2 = rel >> 3;
        const int col = c2 % 192, sb = c2 / 192;
        const int k = (sb >> 2) * 32 + (sb & 3) * 8 + kk;
        v = (col < 96) ? Woff[k * 96 + col] : Waw[k * 96 + (col - 96)];
        dst = wcat + rel;
    } else if (id < 81920) {
        const int rel = id - 49152;
        const int kk = rel & 7, c2 = rel >> 3;
        const int col = c2 & 127, sb = c2 >> 7;
        const int k = (sb >> 2) * 32 + (sb & 3) * 8 + kk;
        v = Wv[k * 256 + col];
        dst = wvs + rel;
    } else {
        const int rel = id - 81920;
        const int kk = rel & 7, c2 = rel >> 3;
        const int col = c2 & 255, sb = c2 >> 8;
        const int k = (sb >> 2) * 32 + (sb & 3) * 8 + kk;
        v = Wo[k * 256 + col];
        dst = wos + rel;
    }
    *dst = f2bf(v);
    if (id < 192) bcat[id] = (id < 96) ? boff[id] : baw[id - 96];
}

// ---------------------------------------------------------------------------
// K12: merged independent GEMMs in one dispatch.
//  blocks 0..223  : value projection tile (128 rows x 128 cols, K=256)
//  blocks 224..479: logits tile (64 queries x 192 cols, K=256) + softmax + sidx
// ---------------------------------------------------------------------------
__global__ __launch_bounds__(256) void fused_k12_kernel(
    const float* __restrict__ v0, const float* __restrict__ v1,
    const float* __restrict__ v2,
    const unsigned short* __restrict__ wvs, const float* __restrict__ bv,
    unsigned short* __restrict__ vproj,
    const float* __restrict__ query,
    const unsigned short* __restrict__ wcat, const float* __restrict__ bcat,
    const float* __restrict__ refp, float* __restrict__ rows)
{
    __shared__ __align__(16) char SMEM[66560];
    const int t = threadIdx.x;
    const int bid = blockIdx.x;
    const int w = t >> 6, lane = t & 63;
    const int fr = lane & 15, sl = lane >> 4;

    if (bid < 224) {
        // ================= vproj path =================
        auto Asub = reinterpret_cast<unsigned short(*)[128][8]>(SMEM);          // [4][128][8]
        auto Bsub = reinterpret_cast<unsigned short(*)[128][8]>(SMEM + 8192);   // [4][128][8]
        auto Epi2 = reinterpret_cast<float(*)[132]>(SMEM + 16384);              // [32][132]

        const int row0 = bid * 128;
        const float* Ap; int arow;
        if (row0 < 16384)      { Ap = v0; arow = row0; }
        else if (row0 < 24576) { Ap = v1; arow = row0 - 16384; }
        else                   { Ap = v2; arow = row0 - 24576; }

        const int ar = t >> 1, ah = t & 1;
        const int wr = w >> 1, wc = w & 1;

        f32x4 acc[4][4];
#pragma unroll
        for (int m = 0; m < 4; ++m)
#pragma unroll
            for (int n = 0; n < 4; ++n) acc[m][n] = (f32x4){0.f, 0.f, 0.f, 0.f};

        for (int k0t = 0; k0t < 8; ++k0t) {
            const int k0 = k0t * 32;
#pragma unroll
            for (int q = 0; q < 2; ++q) {           // stage A (f32 -> bf16)
                const int slot = ah * 2 + q;
                const float* src = &Ap[(size_t)(arow + ar) * 256 + k0 + slot * 8];
                const float4 f0 = *reinterpret_cast<const float4*>(src);
                const float4 f1 = *reinterpret_cast<const float4*>(src + 4);
                u16x8 pk;
                pk[0]=f2bf(f0.x); pk[1]=f2bf(f0.y); pk[2]=f2bf(f0.z); pk[3]=f2bf(f0.w);
                pk[4]=f2bf(f1.x); pk[5]=f2bf(f1.y); pk[6]=f2bf(f1.z); pk[7]=f2bf(f1.w);
                *reinterpret_cast<u16x8*>(&Asub[slot][ar][0]) = pk;
            }
            {                                        // stage B: pure 16B copies
                const u16x8* src = reinterpret_cast<const u16x8*>(wvs + (size_t)k0t * 4096);
#pragma unroll
                for (int i = 0; i < 2; ++i) {
                    const int ch = t + i * 256;      // 0..511
                    *reinterpret_cast<u16x8*>(&Bsub[ch >> 7][ch & 127][0]) = src[ch];
                }
            }
            __syncthreads();

            bf16x8 bfrag[4];
#pragma unroll
            for (int n = 0; n < 4; ++n)
                bfrag[n] = *reinterpret_cast<bf16x8*>(&Bsub[sl][wc * 64 + n * 16 + fr][0]);
#pragma unroll
            for (int m = 0; m < 4; ++m) {
                bf16x8 afrag = *reinterpret_cast<bf16x8*>(&Asub[sl][wr * 64 + m * 16 + fr][0]);
#pragma unroll
                for (int n = 0; n < 4; ++n)
                    acc[m][n] = __builtin_amdgcn_mfma_f32_16x16x32_bf16(afrag, bfrag[n], acc[m][n], 0, 0, 0);
            }
            __syncthreads();
        }

        float bs[4];
#pragma unroll
        for (int n = 0; n < 4; ++n) bs[n] = bv[wc * 64 + n * 16 + fr];

#pragma unroll
        for (int m = 0; m < 4; ++m) {
#pragma unroll
            for (int n = 0; n < 4; ++n)
#pragma unroll
                for (int j = 0; j < 4; ++j)
                    Epi2[wr * 16 + sl * 4 + j][wc * 64 + n * 16 + fr] = acc[m][n][j] + bs[n];
            __syncthreads();
#pragma unroll
            for (int i = 0; i < 2; ++i) {            // 512 short8 chunks, 2/thread
                const int idx = t + i * 256;
                const int rb = idx >> 4, c8 = idx & 15;
                const int grow = row0 + m * 16 + (rb >> 4) * 64 + (rb & 15);
                u16x8 pk;
#pragma unroll
                for (int e = 0; e < 8; ++e) pk[e] = f2bf(Epi2[rb][c8 * 8 + e]);
                *reinterpret_cast<u16x8*>(&vproj[(size_t)grow * 128 + c8 * 8]) = pk;
            }
            __syncthreads();
        }
    } else {
        // ================= logits path =================
        auto Asub = reinterpret_cast<unsigned short(*)[64][8]>(SMEM);           // [4][64][8]
        auto Bsub = reinterpret_cast<unsigned short(*)[192][8]>(SMEM + 4096);   // [4][192][8]
        auto Epi  = reinterpret_cast<float(*)[196]>(SMEM + 16384);              // [64][196]

        const int qrow0 = (bid - 224) * 64;
        const int wr = w >> 1, wc = w & 1;          // wave: 32 rows x 96 cols

        f32x4 acc[2][6];
#pragma unroll
        for (int m = 0; m < 2; ++m)
#pragma unroll
            for (int n = 0; n < 6; ++n) acc[m][n] = (f32x4){0.f, 0.f, 0.f, 0.f};

        const int ar = t >> 2, as = t & 3;          // A staging: row 0..63, slot 0..3

        for (int k0t = 0; k0t < 8; ++k0t) {
            const int k0 = k0t * 32;
            {   // stage A: 64 rows x 32 k, f32 -> bf16
                const float* src = &query[(size_t)(qrow0 + ar) * 256 + k0 + as * 8];
                const float4 f0 = *reinterpret_cast<const float4*>(src);
                const float4 f1 = *reinterpret_cast<const float4*>(src + 4);
                u16x8 pk;
                pk[0]=f2bf(f0.x); pk[1]=f2bf(f0.y); pk[2]=f2bf(f0.z); pk[3]=f2bf(f0.w);
                pk[4]=f2bf(f1.x); pk[5]=f2bf(f1.y); pk[6]=f2bf(f1.z); pk[7]=f2bf(f1.w);
                *reinterpret_cast<u16x8*>(&Asub[as][ar][0]) = pk;
            }
            {   // stage B: pure 16B copies from pre-swizzled wcat
                const u16x8* src = reinterpret_cast<const u16x8*>(&wcat[(size_t)k0t * 6144]);
#pragma unroll
                for (int i = 0; i < 3; ++i) {
                    const int c = t + i * 256;      // 0..767
                    *reinterpret_cast<u16x8*>(&Bsub[c / 192][c % 192][0]) = src[c];
                }
            }
            __syncthreads();

            bf16x8 bfrag[6];
#pragma unroll
            for (int n = 0; n < 6; ++n)
                bfrag[n] = *reinterpret_cast<bf16x8*>(&Bsub[sl][wc * 96 + n * 16 + fr][0]);
#pragma unroll
            for (int m = 0; m < 2; ++m) {
                bf16x8 afrag = *reinterpret_cast<bf16x8*>(&Asub[sl][wr * 32 + m * 16 + fr][0]);
#pragma unroll
                for (int n = 0; n < 6; ++n)
                    acc[m][n] = __builtin_amdgcn_mfma_f32_16x16x32_bf16(afrag, bfrag[n], acc[m][n], 0, 0, 0);
            }
            __syncthreads();
        }

        // acc -> Epi (logits + bias)
#pragma unroll
        for (int n = 0; n < 6; ++n) {
            const int col = wc * 96 + n * 16 + fr;
            const float bsn = bcat[col];
#pragma unroll
            for (int m = 0; m < 2; ++m)
#pragma unroll
                for (int j = 0; j < 4; ++j)
                    Epi[wr * 32 + m * 16 + sl * 4 + j][col] = acc[m][n][j] + bsn;
        }
        __syncthreads();

        // In-place per-head softmax (cols 96..191) + sidx (cols 0..95).
#pragma unroll
        for (int i = 0; i < 2; ++i) {
            const int p = t + i * 256;
            const int q = p >> 3, h = p & 7;
            const float ref = refp[qrow0 + q];
            float* lg = &Epi[q][96 + h * 12];
            float mx = -1e30f;
#pragma unroll
            for (int jj = 0; jj < 12; ++jj) mx = fmaxf(mx, lg[jj]);
            float e[12]; float s = 0.f;
#pragma unroll
            for (int jj = 0; jj < 12; ++jj) { e[jj] = expf(lg[jj] - mx); s += e[jj]; }
            const float inv = 1.f / s;
#pragma unroll
            for (int jj = 0; jj < 12; ++jj) lg[jj] = e[jj] * inv;
            float* off = &Epi[q][h * 12];
#pragma unroll
            for (int jj = 0; jj < 12; ++jj) {
                const int l = jj >> 2;
                const int T = 2048 >> l;
                float pos = ref + off[jj] / (float)T;
                pos = fminf(fmaxf(pos, 0.f), 1.f);
                off[jj] = pos * (float)(T - 1);
            }
        }
        __syncthreads();

        // Coalesced writeout: 64 x 192 f32 = 3072 float4, 12 per thread.
#pragma unroll
        for (int i = 0; i < 12; ++i) {
            const int idx = t + i * 256;
            const int q = idx / 48, c4 = idx % 48;
            const float4 o = *reinterpret_cast<const float4*>(&Epi[q][c4 * 4]);
            *reinterpret_cast<float4*>(&rows[(size_t)(qrow0 + q) * 192 + c4 * 4]) = o;
        }
    }
}

// ---------------------------------------------------------------------------
// K3: gather + lerp + weighted sum. rows[bq][j]=sidx, rows[bq][96+j]=aw.
// XCD swizzle: bq = (bid&7)*2048 + (bid>>3) -> per-XCD batch locality.
// ---------------------------------------------------------------------------
__global__ __launch_bounds__(256) void sample_kernel(
    const float* __restrict__ rows,            // [16384,192]  sidx | aw
    const unsigned short* __restrict__ vproj,  // [28672,128]  bf16, level-major
    unsigned short* __restrict__ out_mid)      // [16384,256]  bf16
{
    const int bid = blockIdx.x;
    const int bq = ((bid & 7) << 11) | (bid >> 3);
    const int b = bq >> 11;
    const int t = threadIdx.x;
    const int h = t >> 5, c = t & 31;
    __shared__ float srow[192];
    if (t < 192) srow[t] = rows[(size_t)bq * 192 + t];
    __syncthreads();
    float acc = 0.f;
#pragma unroll
    for (int l = 0; l < 3; ++l) {
        const int T = 2048 >> l;
        const int loff = (l == 0) ? 0 : ((l == 1) ? 16384 : 24576);
#pragma unroll
        for (int p = 0; p < 4; ++p) {
            const int j = h * 12 + l * 4 + p;
            const float wgt  = srow[96 + j];
            const float sidx = srow[j];
            int ifl = (int)sidx;
            ifl = min(max(ifl, 0), T - 2);
            const float wce = sidx - (float)ifl;
            const size_t base = ((size_t)(loff + b * T + ifl)) * 128 + p * 32 + c;
            const float vf = bf2f(vproj[base]);
            const float vc = bf2f(vproj[base + 128]);
            acc += wgt * (vf + wce * (vc - vf));
        }
    }
    out_mid[(size_t)bq * 256 + t] = f2bf(acc);
}

// ---------------------------------------------------------------------------
// K4: output projection. out[16384,256] f32 = omid(bf16) @ Wo + bo.
// Tile 128x128, B from pre-swizzled wos (pure 16B copies).
// ---------------------------------------------------------------------------
__global__ __launch_bounds__(256) void outproj_kernel(
    const unsigned short* __restrict__ omid,   // [16384,256] bf16
    const unsigned short* __restrict__ wos,    // pre-swizzled [8][4][256][8]
    const float* __restrict__ bo,
    float* __restrict__ out)
{
    __shared__ unsigned short Asub[4][128][8];  // 8 KB
    __shared__ unsigned short Bsub[4][128][8];  // 8 KB
    __shared__ float Epi2[32][132];             // 16.5 KB

    const int t = threadIdx.x;
    const int row0 = blockIdx.y * 128;
    const int col0 = blockIdx.x * 128;

    const int ar = t >> 1, ah = t & 1;
    const int w = t >> 6, lane = t & 63;
    const int wr = w >> 1, wc = w & 1;
    const int fr = lane & 15, sl = lane >> 4;

    f32x4 acc[4][4];
#pragma unroll
    for (int m = 0; m < 4; ++m)
#pragma unroll
        for (int n = 0; n < 4; ++n) acc[m][n] = (f32x4){0.f, 0.f, 0.f, 0.f};

    for (int k0t = 0; k0t < 8; ++k0t) {
        const int k0 = k0t * 32;
#pragma unroll
        for (int q = 0; q < 2; ++q) {           // stage A: 16B copies (bf16 src)
            const int slot = ah * 2 + q;
            *reinterpret_cast<u16x8*>(&Asub[slot][ar][0]) =
                *reinterpret_cast<const u16x8*>(&omid[(size_t)(row0 + ar) * 256 + k0 + slot * 8]);
        }
        {                                        // stage B: 16B copies from wos
            const u16x8* src = reinterpret_cast<const u16x8*>(wos + (size_t)k0t * 8192);
#pragma unroll
            for (int i = 0; i < 2; ++i) {
                const int ch = t + i * 256;      // 0..511
                *reinterpret_cast<u16x8*>(&Bsub[ch >> 7][ch & 127][0]) =
                    src[(ch >> 7) * 256 + col0 + (ch & 127)];
            }
        }
        __syncthreads();

        bf16x8 bfrag[4];
#pragma unroll
        for (int n = 0; n < 4; ++n)
            bfrag[n] = *reinterpret_cast<bf16x8*>(&Bsub[sl][wc * 64 + n * 16 + fr][0]);
#pragma unroll
        for (int m = 0; m < 4; ++m) {
            bf16x8 afrag = *reinterpret_cast<bf16x8*>(&Asub[sl][wr * 64 + m * 16 + fr][0]);
#pragma unroll
            for (int n = 0; n < 4; ++n)
                acc[m][n] = __builtin_amdgcn_mfma_f32_16x16x32_bf16(afrag, bfrag[n], acc[m][n], 0, 0, 0);
        }
        __syncthreads();
    }

    float bs[4];
#pragma unroll
    for (int n = 0; n < 4; ++n) bs[n] = bo[col0 + wc * 64 + n * 16 + fr];

#pragma unroll
    for (int m = 0; m < 4; ++m) {
#pragma unroll
        for (int n = 0; n < 4; ++n)
#pragma unroll
            for (int j = 0; j < 4; ++j)
                Epi2[wr * 16 + sl * 4 + j][wc * 64 + n * 16 + fr] = acc[m][n][j] + bs[n];
        __syncthreads();
#pragma unroll
        for (int i = 0; i < 4; ++i) {            // 1024 float4 chunks, 4/thread
            const int idx = t + i * 256;
            const int rb = idx >> 5, c4 = idx & 31;
            const int grow = row0 + m * 16 + (rb >> 4) * 64 + (rb & 15);
            const float4 o = *reinterpret_cast<const float4*>(&Epi2[rb][c4 * 4]);
            *reinterpret_cast<float4*>(&out[(size_t)grow * 256 + col0 + c4 * 4]) = o;
        }
        __syncthreads();
    }
}

extern "C" void kernel_launch(void* const* d_in, const int* in_sizes, int n_in,
                              void* d_out, int out_size, void* d_ws, size_t ws_size,
                              hipStream_t stream) {
    (void)in_sizes; (void)n_in; (void)out_size; (void)ws_size;
    const float* query = (const float*)d_in[0];
    const float* refp  = (const float*)d_in[1];
    const float* v0    = (const float*)d_in[2];
    const float* v1    = (const float*)d_in[3];
    const float* v2    = (const float*)d_in[4];
    const float* Woff  = (const float*)d_in[5];
    const float* boff  = (const float*)d_in[6];
    const float* Waw   = (const float*)d_in[7];
    const float* baw   = (const float*)d_in[8];
    const float* Wv    = (const float*)d_in[9];
    const float* bv    = (const float*)d_in[10];
    const float* Wo    = (const float*)d_in[11];
    const float* bo    = (const float*)d_in[12];
    float* out = (float*)d_out;

    char* ws = (char*)d_ws;
    unsigned short* vproj = (unsigned short*)(ws);             // 7,340,032 B
    float*          rows  = (float*)(ws + 7340032);            // 12,582,912 B
    unsigned short* omid  = (unsigned short*)(ws + 19922944);  // 8,388,608 B
    unsigned short* wcat  = (unsigned short*)(ws + 28311552);  //    98,304 B
    unsigned short* wvs   = (unsigned short*)(ws + 28409856);  //    65,536 B
    unsigned short* wos   = (unsigned short*)(ws + 28475392);  //   131,072 B
    float*          bcat  = (float*)(ws + 28606464);           //       768 B

    // K0: weight pre-swizzle (bf16, staging layout)
    swizzle_w_kernel<<<576, 256, 0, stream>>>(Woff, Waw, boff, baw, Wv, Wo,
                                              wcat, wvs, wos, bcat);

    // K12: merged vproj (blocks 0..223) + logits/softmax/sidx (blocks 224..479)
    fused_k12_kernel<<<480, 256, 0, stream>>>(v0, v1, v2, wvs, bv, vproj,
                                              query, wcat, bcat, refp, rows);

    // K3: gather + lerp + weighted sum (XCD-swizzled)
    sample_kernel<<<16384, 256, 0, stream>>>(rows, vproj, omid);

    // K4: output projection
    outproj_kernel<<<dim3(2, 128), 256, 0, stream>>>(omid, wos, bo, out);
}

// Round 7
// 54.251 us; speedup vs baseline: 2.5940x; 1.1061x over previous
//
#include <hip/hip_runtime.h>
#include <stdint.h>

// B=8, Q=2048, D=256, H=8, L=3, P=4, HD=32
// vproj rows: level-major, T={2048,1024,512}, LOFF={0,16384,24576}, total 28672

typedef __attribute__((ext_vector_type(8))) short bf16x8;
typedef __attribute__((ext_vector_type(8))) unsigned short u16x8;
typedef __attribute__((ext_vector_type(4))) float f32x4;

__device__ __forceinline__ unsigned short f2bf(float f) {
    union { float f; uint32_t u; } v; v.f = f;
    return (unsigned short)((v.u + 0x7FFFu + ((v.u >> 16) & 1u)) >> 16);  // RNE
}
__device__ __forceinline__ float bf2f(unsigned short u) {
    union { uint32_t u; float f; } v; v.u = ((uint32_t)u) << 16;
    return v.f;
}

// ---------------------------------------------------------------------------
// K0: pre-swizzle all weights to bf16 in the GEMM staging layout
// [k0t][slot][col][kk]  (k = k0t*32 + slot*8 + kk), so B-staging = memcpy.
//  seg0: Wcat = [Woff|Waw]  192 cols   (ids 0..49151)
//  seg1: Wv cols 0..127     128 cols   (ids 49152..81919)
//  seg2: Wo                 256 cols   (ids 81920..147455)
// Plus bcat[192] = [boff|baw] f32.
// ---------------------------------------------------------------------------
__global__ __launch_bounds__(256) void swizzle_w_kernel(
    const float* __restrict__ Woff, const float* __restrict__ Waw,
    const float* __restrict__ boff, const float* __restrict__ baw,
    const float* __restrict__ Wv, const float* __restrict__ Wo,
    unsigned short* __restrict__ wcat, unsigned short* __restrict__ wvs,
    unsigned short* __restrict__ wos, float* __restrict__ bcat)
{
    const int id = blockIdx.x * 256 + threadIdx.x;   // 0..147455
    float v; unsigned short* dst;
    if (id < 49152) {
        const int rel = id;
        const int kk = rel & 7, c2 = rel >> 3;
        const int col = c2 % 192, sb = c2 / 192;
        const int k = (sb >> 2) * 32 + (sb & 3) * 8 + kk;
        v = (col < 96) ? Woff[k * 96 + col] : Waw[k * 96 + (col - 96)];
        dst = wcat + rel;
    } else if (id < 81920) {
        const int rel = id - 49152;
        const int kk = rel & 7, c2 = rel >> 3;
        const int col = c2 & 127, sb = c2 >> 7;
        const int k = (sb >> 2) * 32 + (sb & 3) * 8 + kk;
        v = Wv[k * 256 + col];
        dst = wvs + rel;
    } else {
        const int rel = id - 81920;
        const int kk = rel & 7, c2 = rel >> 3;
        const int col = c2 & 255, sb = c2 >> 8;
        const int k = (sb >> 2) * 32 + (sb & 3) * 8 + kk;
        v = Wo[k * 256 + col];
        dst = wos + rel;
    }
    *dst = f2bf(v);
    if (id < 192) bcat[id] = (id < 96) ? boff[id] : baw[id - 96];
}

// ---------------------------------------------------------------------------
// K12: merged independent GEMMs in one dispatch.
//  blocks 0..223  : value projection tile (128 rows x 128 cols, K=256)
//  blocks 224..479: logits tile (64 queries x 192 cols, K=256) + softmax + sidx
// ---------------------------------------------------------------------------
__global__ __launch_bounds__(256) void fused_k12_kernel(
    const float* __restrict__ v0, const float* __restrict__ v1,
    const float* __restrict__ v2,
    const unsigned short* __restrict__ wvs, const float* __restrict__ bv,
    unsigned short* __restrict__ vproj,
    const float* __restrict__ query,
    const unsigned short* __restrict__ wcat, const float* __restrict__ bcat,
    const float* __restrict__ refp, float* __restrict__ rows)
{
    __shared__ __align__(16) char SMEM[66560];
    const int t = threadIdx.x;
    const int bid = blockIdx.x;
    const int w = t >> 6, lane = t & 63;
    const int fr = lane & 15, sl = lane >> 4;

    if (bid < 224) {
        // ================= vproj path =================
        auto Asub = reinterpret_cast<unsigned short(*)[128][8]>(SMEM);          // [4][128][8]
        auto Bsub = reinterpret_cast<unsigned short(*)[128][8]>(SMEM + 8192);   // [4][128][8]
        auto Epi2 = reinterpret_cast<float(*)[132]>(SMEM + 16384);              // [32][132]

        const int row0 = bid * 128;
        const float* Ap; int arow;
        if (row0 < 16384)      { Ap = v0; arow = row0; }
        else if (row0 < 24576) { Ap = v1; arow = row0 - 16384; }
        else                   { Ap = v2; arow = row0 - 24576; }

        const int ar = t >> 1, ah = t & 1;
        const int wr = w >> 1, wc = w & 1;

        f32x4 acc[4][4];
#pragma unroll
        for (int m = 0; m < 4; ++m)
#pragma unroll
            for (int n = 0; n < 4; ++n) acc[m][n] = (f32x4){0.f, 0.f, 0.f, 0.f};

        for (int k0t = 0; k0t < 8; ++k0t) {
            const int k0 = k0t * 32;
#pragma unroll
            for (int q = 0; q < 2; ++q) {           // stage A (f32 -> bf16)
                const int slot = ah * 2 + q;
                const float* src = &Ap[(size_t)(arow + ar) * 256 + k0 + slot * 8];
                const float4 f0 = *reinterpret_cast<const float4*>(src);
                const float4 f1 = *reinterpret_cast<const float4*>(src + 4);
                u16x8 pk;
                pk[0]=f2bf(f0.x); pk[1]=f2bf(f0.y); pk[2]=f2bf(f0.z); pk[3]=f2bf(f0.w);
                pk[4]=f2bf(f1.x); pk[5]=f2bf(f1.y); pk[6]=f2bf(f1.z); pk[7]=f2bf(f1.w);
                *reinterpret_cast<u16x8*>(&Asub[slot][ar][0]) = pk;
            }
            {                                        // stage B: pure 16B copies
                const u16x8* src = reinterpret_cast<const u16x8*>(wvs + (size_t)k0t * 4096);
#pragma unroll
                for (int i = 0; i < 2; ++i) {
                    const int ch = t + i * 256;      // 0..511
                    *reinterpret_cast<u16x8*>(&Bsub[ch >> 7][ch & 127][0]) = src[ch];
                }
            }
            __syncthreads();

            bf16x8 bfrag[4];
#pragma unroll
            for (int n = 0; n < 4; ++n)
                bfrag[n] = *reinterpret_cast<bf16x8*>(&Bsub[sl][wc * 64 + n * 16 + fr][0]);
#pragma unroll
            for (int m = 0; m < 4; ++m) {
                bf16x8 afrag = *reinterpret_cast<bf16x8*>(&Asub[sl][wr * 64 + m * 16 + fr][0]);
#pragma unroll
                for (int n = 0; n < 4; ++n)
                    acc[m][n] = __builtin_amdgcn_mfma_f32_16x16x32_bf16(afrag, bfrag[n], acc[m][n], 0, 0, 0);
            }
            __syncthreads();
        }

        float bs[4];
#pragma unroll
        for (int n = 0; n < 4; ++n) bs[n] = bv[wc * 64 + n * 16 + fr];

#pragma unroll
        for (int m = 0; m < 4; ++m) {
#pragma unroll
            for (int n = 0; n < 4; ++n)
#pragma unroll
                for (int j = 0; j < 4; ++j)
                    Epi2[wr * 16 + sl * 4 + j][wc * 64 + n * 16 + fr] = acc[m][n][j] + bs[n];
            __syncthreads();
#pragma unroll
            for (int i = 0; i < 2; ++i) {            // 512 short8 chunks, 2/thread
                const int idx = t + i * 256;
                const int rb = idx >> 4, c8 = idx & 15;
                const int grow = row0 + m * 16 + (rb >> 4) * 64 + (rb & 15);
                u16x8 pk;
#pragma unroll
                for (int e = 0; e < 8; ++e) pk[e] = f2bf(Epi2[rb][c8 * 8 + e]);
                *reinterpret_cast<u16x8*>(&vproj[(size_t)grow * 128 + c8 * 8]) = pk;
            }
            __syncthreads();
        }
    } else {
        // ================= logits path =================
        auto Asub = reinterpret_cast<unsigned short(*)[64][8]>(SMEM);           // [4][64][8]
        auto Bsub = reinterpret_cast<unsigned short(*)[192][8]>(SMEM + 4096);   // [4][192][8]
        auto Epi  = reinterpret_cast<float(*)[196]>(SMEM + 16384);              // [64][196]

        const int qrow0 = (bid - 224) * 64;
        const int wr = w >> 1, wc = w & 1;          // wave: 32 rows x 96 cols

        f32x4 acc[2][6];
#pragma unroll
        for (int m = 0; m < 2; ++m)
#pragma unroll
            for (int n = 0; n < 6; ++n) acc[m][n] = (f32x4){0.f, 0.f, 0.f, 0.f};

        const int ar = t >> 2, as = t & 3;          // A staging: row 0..63, slot 0..3

        for (int k0t = 0; k0t < 8; ++k0t) {
            const int k0 = k0t * 32;
            {   // stage A: 64 rows x 32 k, f32 -> bf16
                const float* src = &query[(size_t)(qrow0 + ar) * 256 + k0 + as * 8];
                const float4 f0 = *reinterpret_cast<const float4*>(src);
                const float4 f1 = *reinterpret_cast<const float4*>(src + 4);
                u16x8 pk;
                pk[0]=f2bf(f0.x); pk[1]=f2bf(f0.y); pk[2]=f2bf(f0.z); pk[3]=f2bf(f0.w);
                pk[4]=f2bf(f1.x); pk[5]=f2bf(f1.y); pk[6]=f2bf(f1.z); pk[7]=f2bf(f1.w);
                *reinterpret_cast<u16x8*>(&Asub[as][ar][0]) = pk;
            }
            {   // stage B: pure 16B copies from pre-swizzled wcat
                const u16x8* src = reinterpret_cast<const u16x8*>(&wcat[(size_t)k0t * 6144]);
#pragma unroll
                for (int i = 0; i < 3; ++i) {
                    const int c = t + i * 256;      // 0..767
                    *reinterpret_cast<u16x8*>(&Bsub[c / 192][c % 192][0]) = src[c];
                }
            }
            __syncthreads();

            bf16x8 bfrag[6];
#pragma unroll
            for (int n = 0; n < 6; ++n)
                bfrag[n] = *reinterpret_cast<bf16x8*>(&Bsub[sl][wc * 96 + n * 16 + fr][0]);
#pragma unroll
            for (int m = 0; m < 2; ++m) {
                bf16x8 afrag = *reinterpret_cast<bf16x8*>(&Asub[sl][wr * 32 + m * 16 + fr][0]);
#pragma unroll
                for (int n = 0; n < 6; ++n)
                    acc[m][n] = __builtin_amdgcn_mfma_f32_16x16x32_bf16(afrag, bfrag[n], acc[m][n], 0, 0, 0);
            }
            __syncthreads();
        }

        // acc -> Epi (logits + bias)
#pragma unroll
        for (int n = 0; n < 6; ++n) {
            const int col = wc * 96 + n * 16 + fr;
            const float bsn = bcat[col];
#pragma unroll
            for (int m = 0; m < 2; ++m)
#pragma unroll
                for (int j = 0; j < 4; ++j)
                    Epi[wr * 32 + m * 16 + sl * 4 + j][col] = acc[m][n][j] + bsn;
        }
        __syncthreads();

        // In-place per-head softmax (cols 96..191) + sidx (cols 0..95).
#pragma unroll
        for (int i = 0; i < 2; ++i) {
            const int p = t + i * 256;
            const int q = p >> 3, h = p & 7;
            const float ref = refp[qrow0 + q];
            float* lg = &Epi[q][96 + h * 12];
            float mx = -1e30f;
#pragma unroll
            for (int jj = 0; jj < 12; ++jj) mx = fmaxf(mx, lg[jj]);
            float e[12]; float s = 0.f;
#pragma unroll
            for (int jj = 0; jj < 12; ++jj) { e[jj] = expf(lg[jj] - mx); s += e[jj]; }
            const float inv = 1.f / s;
#pragma unroll
            for (int jj = 0; jj < 12; ++jj) lg[jj] = e[jj] * inv;
            float* off = &Epi[q][h * 12];
#pragma unroll
            for (int jj = 0; jj < 12; ++jj) {
                const int l = jj >> 2;
                const int T = 2048 >> l;
                float pos = ref + off[jj] / (float)T;
                pos = fminf(fmaxf(pos, 0.f), 1.f);
                off[jj] = pos * (float)(T - 1);
            }
        }
        __syncthreads();

        // Coalesced writeout: 64 x 192 f32 = 3072 float4, 12 per thread.
#pragma unroll
        for (int i = 0; i < 12; ++i) {
            const int idx = t + i * 256;
            const int q = idx / 48, c4 = idx % 48;
            const float4 o = *reinterpret_cast<const float4*>(&Epi[q][c4 * 4]);
            *reinterpret_cast<float4*>(&rows[(size_t)(qrow0 + q) * 192 + c4 * 4]) = o;
        }
    }
}

// ---------------------------------------------------------------------------
// K3: gather + lerp + weighted sum, 4x vectorized.
// One wave per query (8 heads x 8 channel-quads), 4 queries per block.
// ushort4 (8B) gathers; grid 4096 with bid&7 = batch -> XCD L2 affinity.
// ---------------------------------------------------------------------------
__global__ __launch_bounds__(256) void sample_kernel(
    const float* __restrict__ rows,            // [16384,192]  sidx | aw
    const unsigned short* __restrict__ vproj,  // [28672,128]  bf16, level-major
    unsigned short* __restrict__ out_mid)      // [16384,256]  bf16
{
    const int bid = blockIdx.x;                // 0..4095
    const int b = bid & 7;
    const int q0 = (b << 11) + ((bid >> 3) << 2);   // 4 queries/block
    const int t = threadIdx.x;
    const int w = t >> 6, lane = t & 63;
    const int h = lane >> 3, c4 = lane & 7;    // channel = c4*4 .. +3

    __shared__ float srow[4][192];
    {
        const float* src = rows + (size_t)q0 * 192;
#pragma unroll
        for (int i = 0; i < 3; ++i) {
            const int idx = t + i * 256;       // 0..767, coalesced
            srow[idx / 192][idx % 192] = src[idx];
        }
    }
    __syncthreads();

    float acc0 = 0.f, acc1 = 0.f, acc2 = 0.f, acc3 = 0.f;
#pragma unroll
    for (int l = 0; l < 3; ++l) {
        const int T = 2048 >> l;
        const int loff = (l == 0) ? 0 : ((l == 1) ? 16384 : 24576);
#pragma unroll
        for (int p = 0; p < 4; ++p) {
            const int j = h * 12 + l * 4 + p;
            const float wgt  = srow[w][96 + j];
            const float sidx = srow[w][j];
            int ifl = (int)sidx;
            ifl = min(max(ifl, 0), T - 2);
            const float wce = sidx - (float)ifl;
            const size_t base = ((size_t)(loff + b * T + ifl)) * 128 + p * 32 + c4 * 4;
            const ushort4 vf = *reinterpret_cast<const ushort4*>(&vproj[base]);
            const ushort4 vc = *reinterpret_cast<const ushort4*>(&vproj[base + 128]);
            const float f0 = bf2f(vf.x), f1 = bf2f(vf.y), f2 = bf2f(vf.z), f3 = bf2f(vf.w);
            const float g0 = bf2f(vc.x), g1 = bf2f(vc.y), g2 = bf2f(vc.z), g3 = bf2f(vc.w);
            acc0 += wgt * (f0 + wce * (g0 - f0));
            acc1 += wgt * (f1 + wce * (g1 - f1));
            acc2 += wgt * (f2 + wce * (g2 - f2));
            acc3 += wgt * (f3 + wce * (g3 - f3));
        }
    }
    ushort4 o;
    o.x = f2bf(acc0); o.y = f2bf(acc1); o.z = f2bf(acc2); o.w = f2bf(acc3);
    *reinterpret_cast<ushort4*>(&out_mid[(size_t)(q0 + w) * 256 + h * 32 + c4 * 4]) = o;
}

// ---------------------------------------------------------------------------
// K4: output projection. out[16384,256] f32 = omid(bf16) @ Wo + bo.
// Tile 128x128, B from pre-swizzled wos (pure 16B copies).
// ---------------------------------------------------------------------------
__global__ __launch_bounds__(256) void outproj_kernel(
    const unsigned short* __restrict__ omid,   // [16384,256] bf16
    const unsigned short* __restrict__ wos,    // pre-swizzled [8][4][256][8]
    const float* __restrict__ bo,
    float* __restrict__ out)
{
    __shared__ unsigned short Asub[4][128][8];  // 8 KB
    __shared__ unsigned short Bsub[4][128][8];  // 8 KB
    __shared__ float Epi2[32][132];             // 16.5 KB

    const int t = threadIdx.x;
    const int row0 = blockIdx.y * 128;
    const int col0 = blockIdx.x * 128;

    const int ar = t >> 1, ah = t & 1;
    const int w = t >> 6, lane = t & 63;
    const int wr = w >> 1, wc = w & 1;
    const int fr = lane & 15, sl = lane >> 4;

    f32x4 acc[4][4];
#pragma unroll
    for (int m = 0; m < 4; ++m)
#pragma unroll
        for (int n = 0; n < 4; ++n) acc[m][n] = (f32x4){0.f, 0.f, 0.f, 0.f};

    for (int k0t = 0; k0t < 8; ++k0t) {
        const int k0 = k0t * 32;
#pragma unroll
        for (int q = 0; q < 2; ++q) {           // stage A: 16B copies (bf16 src)
            const int slot = ah * 2 + q;
            *reinterpret_cast<u16x8*>(&Asub[slot][ar][0]) =
                *reinterpret_cast<const u16x8*>(&omid[(size_t)(row0 + ar) * 256 + k0 + slot * 8]);
        }
        {                                        // stage B: 16B copies from wos
            const u16x8* src = reinterpret_cast<const u16x8*>(wos + (size_t)k0t * 8192);
#pragma unroll
            for (int i = 0; i < 2; ++i) {
                const int ch = t + i * 256;      // 0..511
                *reinterpret_cast<u16x8*>(&Bsub[ch >> 7][ch & 127][0]) =
                    src[(ch >> 7) * 256 + col0 + (ch & 127)];
            }
        }
        __syncthreads();

        bf16x8 bfrag[4];
#pragma unroll
        for (int n = 0; n < 4; ++n)
            bfrag[n] = *reinterpret_cast<bf16x8*>(&Bsub[sl][wc * 64 + n * 16 + fr][0]);
#pragma unroll
        for (int m = 0; m < 4; ++m) {
            bf16x8 afrag = *reinterpret_cast<bf16x8*>(&Asub[sl][wr * 64 + m * 16 + fr][0]);
#pragma unroll
            for (int n = 0; n < 4; ++n)
                acc[m][n] = __builtin_amdgcn_mfma_f32_16x16x32_bf16(afrag, bfrag[n], acc[m][n], 0, 0, 0);
        }
        __syncthreads();
    }

    float bs[4];
#pragma unroll
    for (int n = 0; n < 4; ++n) bs[n] = bo[col0 + wc * 64 + n * 16 + fr];

#pragma unroll
    for (int m = 0; m < 4; ++m) {
#pragma unroll
        for (int n = 0; n < 4; ++n)
#pragma unroll
            for (int j = 0; j < 4; ++j)
                Epi2[wr * 16 + sl * 4 + j][wc * 64 + n * 16 + fr] = acc[m][n][j] + bs[n];
        __syncthreads();
#pragma unroll
        for (int i = 0; i < 4; ++i) {            // 1024 float4 chunks, 4/thread
            const int idx = t + i * 256;
            const int rb = idx >> 5, c4 = idx & 31;
            const int grow = row0 + m * 16 + (rb >> 4) * 64 + (rb & 15);
            const float4 o = *reinterpret_cast<const float4*>(&Epi2[rb][c4 * 4]);
            *reinterpret_cast<float4*>(&out[(size_t)grow * 256 + col0 + c4 * 4]) = o;
        }
        __syncthreads();
    }
}

extern "C" void kernel_launch(void* const* d_in, const int* in_sizes, int n_in,
                              void* d_out, int out_size, void* d_ws, size_t ws_size,
                              hipStream_t stream) {
    (void)in_sizes; (void)n_in; (void)out_size; (void)ws_size;
    const float* query = (const float*)d_in[0];
    const float* refp  = (const float*)d_in[1];
    const float* v0    = (const float*)d_in[2];
    const float* v1    = (const float*)d_in[3];
    const float* v2    = (const float*)d_in[4];
    const float* Woff  = (const float*)d_in[5];
    const float* boff  = (const float*)d_in[6];
    const float* Waw   = (const float*)d_in[7];
    const float* baw   = (const float*)d_in[8];
    const float* Wv    = (const float*)d_in[9];
    const float* bv    = (const float*)d_in[10];
    const float* Wo    = (const float*)d_in[11];
    const float* bo    = (const float*)d_in[12];
    float* out = (float*)d_out;

    char* ws = (char*)d_ws;
    unsigned short* vproj = (unsigned short*)(ws);             // 7,340,032 B
    float*          rows  = (float*)(ws + 7340032);            // 12,582,912 B
    unsigned short* omid  = (unsigned short*)(ws + 19922944);  // 8,388,608 B
    unsigned short* wcat  = (unsigned short*)(ws + 28311552);  //    98,304 B
    unsigned short* wvs   = (unsigned short*)(ws + 28409856);  //    65,536 B
    unsigned short* wos   = (unsigned short*)(ws + 28475392);  //   131,072 B
    float*          bcat  = (float*)(ws + 28606464);           //       768 B

    // K0: weight pre-swizzle (bf16, staging layout)
    swizzle_w_kernel<<<576, 256, 0, stream>>>(Woff, Waw, boff, baw, Wv, Wo,
                                              wcat, wvs, wos, bcat);

    // K12: merged vproj (blocks 0..223) + logits/softmax/sidx (blocks 224..479)
    fused_k12_kernel<<<480, 256, 0, stream>>>(v0, v1, v2, wvs, bv, vproj,
                                              query, wcat, bcat, refp, rows);

    // K3: gather + lerp + weighted sum (vectorized, XCD-swizzled)
    sample_kernel<<<4096, 256, 0, stream>>>(rows, vproj, omid);

    // K4: output projection
    outproj_kernel<<<dim3(2, 128), 256, 0, stream>>>(omid, wos, bo, out);
}

// Round 8
// 53.745 us; speedup vs baseline: 2.6184x; 1.0094x over previous
//
#include <hip/hip_runtime.h>
#include <stdint.h>

// B=8, Q=2048, D=256, H=8, L=3, P=4, HD=32
// vproj rows: level-major, T={2048,1024,512}, LOFF={0,16384,24576}, total 28672

typedef __attribute__((ext_vector_type(8))) short bf16x8;
typedef __attribute__((ext_vector_type(8))) unsigned short u16x8;
typedef __attribute__((ext_vector_type(4))) float f32x4;

__device__ __forceinline__ unsigned short f2bf(float f) {
    union { float f; uint32_t u; } v; v.f = f;
    return (unsigned short)((v.u + 0x7FFFu + ((v.u >> 16) & 1u)) >> 16);  // RNE
}
__device__ __forceinline__ float bf2f(unsigned short u) {
    union { uint32_t u; float f; } v; v.u = ((uint32_t)u) << 16;
    return v.f;
}

// ---------------------------------------------------------------------------
// K0: pre-swizzle all weights to bf16 in the GEMM staging layout
// [k0t][slot][col][kk]  (k = k0t*32 + slot*8 + kk), so B-staging = memcpy.
// ---------------------------------------------------------------------------
__global__ __launch_bounds__(256) void swizzle_w_kernel(
    const float* __restrict__ Woff, const float* __restrict__ Waw,
    const float* __restrict__ boff, const float* __restrict__ baw,
    const float* __restrict__ Wv, const float* __restrict__ Wo,
    unsigned short* __restrict__ wcat, unsigned short* __restrict__ wvs,
    unsigned short* __restrict__ wos, float* __restrict__ bcat)
{
    const int id = blockIdx.x * 256 + threadIdx.x;   // 0..147455
    float v; unsigned short* dst;
    if (id < 49152) {
        const int rel = id;
        const int kk = rel & 7, c2 = rel >> 3;
        const int col = c2 % 192, sb = c2 / 192;
        const int k = (sb >> 2) * 32 + (sb & 3) * 8 + kk;
        v = (col < 96) ? Woff[k * 96 + col] : Waw[k * 96 + (col - 96)];
        dst = wcat + rel;
    } else if (id < 81920) {
        const int rel = id - 49152;
        const int kk = rel & 7, c2 = rel >> 3;
        const int col = c2 & 127, sb = c2 >> 7;
        const int k = (sb >> 2) * 32 + (sb & 3) * 8 + kk;
        v = Wv[k * 256 + col];
        dst = wvs + rel;
    } else {
        const int rel = id - 81920;
        const int kk = rel & 7, c2 = rel >> 3;
        const int col = c2 & 255, sb = c2 >> 8;
        const int k = (sb >> 2) * 32 + (sb & 3) * 8 + kk;
        v = Wo[k * 256 + col];
        dst = wos + rel;
    }
    *dst = f2bf(v);
    if (id < 192) bcat[id] = (id < 96) ? boff[id] : baw[id - 96];
}

// ---------------------------------------------------------------------------
// K12: merged independent GEMMs in one dispatch, XCD-batch-aligned.
//  blocks 0..223  : value projection tile. batch = bid&7 (XCD affinity),
//                   j = bid>>3 -> (level, tile): j<16 l0, j<24 l1, else l2.
//  blocks 224..479: logits tile. lid = bid-224, batch = lid&7,
//                   q-tile = lid>>3 (0..31).
// ---------------------------------------------------------------------------
__global__ __launch_bounds__(256) void fused_k12_kernel(
    const float* __restrict__ v0, const float* __restrict__ v1,
    const float* __restrict__ v2,
    const unsigned short* __restrict__ wvs, const float* __restrict__ bv,
    unsigned short* __restrict__ vproj,
    const float* __restrict__ query,
    const unsigned short* __restrict__ wcat, const float* __restrict__ bcat,
    const float* __restrict__ refp, float* __restrict__ rows)
{
    __shared__ __align__(16) char SMEM[66560];
    const int t = threadIdx.x;
    const int bid = blockIdx.x;
    const int w = t >> 6, lane = t & 63;
    const int fr = lane & 15, sl = lane >> 4;

    if (bid < 224) {
        // ================= vproj path (XCD-aligned: batch = bid&7) ========
        auto Asub = reinterpret_cast<unsigned short(*)[128][8]>(SMEM);          // [4][128][8]
        auto Bsub = reinterpret_cast<unsigned short(*)[128][8]>(SMEM + 8192);   // [4][128][8]
        auto Epi2 = reinterpret_cast<float(*)[132]>(SMEM + 16384);              // [32][132]

        const int b = bid & 7;
        const int j = bid >> 3;                  // 0..27
        int l, tile;
        if (j < 16)      { l = 0; tile = j; }
        else if (j < 24) { l = 1; tile = j - 16; }
        else             { l = 2; tile = j - 24; }
        const int T = 2048 >> l;
        const int loff = (l == 0) ? 0 : ((l == 1) ? 16384 : 24576);
        const int row0 = loff + b * T + tile * 128;          // vproj dst row
        const int arow = b * T + tile * 128;                 // src row in value_l
        const float* Ap = (l == 0) ? v0 : ((l == 1) ? v1 : v2);

        const int ar = t >> 1, ah = t & 1;
        const int wr = w >> 1, wc = w & 1;

        f32x4 acc[4][4];
#pragma unroll
        for (int m = 0; m < 4; ++m)
#pragma unroll
            for (int n = 0; n < 4; ++n) acc[m][n] = (f32x4){0.f, 0.f, 0.f, 0.f};

        for (int k0t = 0; k0t < 8; ++k0t) {
            const int k0 = k0t * 32;
#pragma unroll
            for (int q = 0; q < 2; ++q) {           // stage A (f32 -> bf16)
                const int slot = ah * 2 + q;
                const float* src = &Ap[(size_t)(arow + ar) * 256 + k0 + slot * 8];
                const float4 f0 = *reinterpret_cast<const float4*>(src);
                const float4 f1 = *reinterpret_cast<const float4*>(src + 4);
                u16x8 pk;
                pk[0]=f2bf(f0.x); pk[1]=f2bf(f0.y); pk[2]=f2bf(f0.z); pk[3]=f2bf(f0.w);
                pk[4]=f2bf(f1.x); pk[5]=f2bf(f1.y); pk[6]=f2bf(f1.z); pk[7]=f2bf(f1.w);
                *reinterpret_cast<u16x8*>(&Asub[slot][ar][0]) = pk;
            }
            {                                        // stage B: pure 16B copies
                const u16x8* src = reinterpret_cast<const u16x8*>(wvs + (size_t)k0t * 4096);
#pragma unroll
                for (int i = 0; i < 2; ++i) {
                    const int ch = t + i * 256;      // 0..511
                    *reinterpret_cast<u16x8*>(&Bsub[ch >> 7][ch & 127][0]) = src[ch];
                }
            }
            __syncthreads();

            bf16x8 bfrag[4];
#pragma unroll
            for (int n = 0; n < 4; ++n)
                bfrag[n] = *reinterpret_cast<bf16x8*>(&Bsub[sl][wc * 64 + n * 16 + fr][0]);
#pragma unroll
            for (int m = 0; m < 4; ++m) {
                bf16x8 afrag = *reinterpret_cast<bf16x8*>(&Asub[sl][wr * 64 + m * 16 + fr][0]);
#pragma unroll
                for (int n = 0; n < 4; ++n)
                    acc[m][n] = __builtin_amdgcn_mfma_f32_16x16x32_bf16(afrag, bfrag[n], acc[m][n], 0, 0, 0);
            }
            __syncthreads();
        }

        float bs[4];
#pragma unroll
        for (int n = 0; n < 4; ++n) bs[n] = bv[wc * 64 + n * 16 + fr];

#pragma unroll
        for (int m = 0; m < 4; ++m) {
#pragma unroll
            for (int n = 0; n < 4; ++n)
#pragma unroll
                for (int jj = 0; jj < 4; ++jj)
                    Epi2[wr * 16 + sl * 4 + jj][wc * 64 + n * 16 + fr] = acc[m][n][jj] + bs[n];
            __syncthreads();
#pragma unroll
            for (int i = 0; i < 2; ++i) {            // 512 short8 chunks, 2/thread
                const int idx = t + i * 256;
                const int rb = idx >> 4, c8 = idx & 15;
                const int grow = row0 + m * 16 + (rb >> 4) * 64 + (rb & 15);
                u16x8 pk;
#pragma unroll
                for (int e = 0; e < 8; ++e) pk[e] = f2bf(Epi2[rb][c8 * 8 + e]);
                *reinterpret_cast<u16x8*>(&vproj[(size_t)grow * 128 + c8 * 8]) = pk;
            }
            __syncthreads();
        }
    } else {
        // ================= logits path (XCD-aligned: batch = lid&7) =======
        auto Asub = reinterpret_cast<unsigned short(*)[64][8]>(SMEM);           // [4][64][8]
        auto Bsub = reinterpret_cast<unsigned short(*)[192][8]>(SMEM + 4096);   // [4][192][8]
        auto Epi  = reinterpret_cast<float(*)[196]>(SMEM + 16384);              // [64][196]

        const int lid = bid - 224;               // 224 % 8 == 0 -> lid&7 == bid&7
        const int qrow0 = (lid & 7) * 2048 + (lid >> 3) * 64;
        const int wr = w >> 1, wc = w & 1;          // wave: 32 rows x 96 cols

        f32x4 acc[2][6];
#pragma unroll
        for (int m = 0; m < 2; ++m)
#pragma unroll
            for (int n = 0; n < 6; ++n) acc[m][n] = (f32x4){0.f, 0.f, 0.f, 0.f};

        const int ar = t >> 2, as = t & 3;          // A staging: row 0..63, slot 0..3

        for (int k0t = 0; k0t < 8; ++k0t) {
            const int k0 = k0t * 32;
            {   // stage A: 64 rows x 32 k, f32 -> bf16
                const float* src = &query[(size_t)(qrow0 + ar) * 256 + k0 + as * 8];
                const float4 f0 = *reinterpret_cast<const float4*>(src);
                const float4 f1 = *reinterpret_cast<const float4*>(src + 4);
                u16x8 pk;
                pk[0]=f2bf(f0.x); pk[1]=f2bf(f0.y); pk[2]=f2bf(f0.z); pk[3]=f2bf(f0.w);
                pk[4]=f2bf(f1.x); pk[5]=f2bf(f1.y); pk[6]=f2bf(f1.z); pk[7]=f2bf(f1.w);
                *reinterpret_cast<u16x8*>(&Asub[as][ar][0]) = pk;
            }
            {   // stage B: pure 16B copies from pre-swizzled wcat
                const u16x8* src = reinterpret_cast<const u16x8*>(&wcat[(size_t)k0t * 6144]);
#pragma unroll
                for (int i = 0; i < 3; ++i) {
                    const int c = t + i * 256;      // 0..767
                    *reinterpret_cast<u16x8*>(&Bsub[c / 192][c % 192][0]) = src[c];
                }
            }
            __syncthreads();

            bf16x8 bfrag[6];
#pragma unroll
            for (int n = 0; n < 6; ++n)
                bfrag[n] = *reinterpret_cast<bf16x8*>(&Bsub[sl][wc * 96 + n * 16 + fr][0]);
#pragma unroll
            for (int m = 0; m < 2; ++m) {
                bf16x8 afrag = *reinterpret_cast<bf16x8*>(&Asub[sl][wr * 32 + m * 16 + fr][0]);
#pragma unroll
                for (int n = 0; n < 6; ++n)
                    acc[m][n] = __builtin_amdgcn_mfma_f32_16x16x32_bf16(afrag, bfrag[n], acc[m][n], 0, 0, 0);
            }
            __syncthreads();
        }

        // acc -> Epi (logits + bias)
#pragma unroll
        for (int n = 0; n < 6; ++n) {
            const int col = wc * 96 + n * 16 + fr;
            const float bsn = bcat[col];
#pragma unroll
            for (int m = 0; m < 2; ++m)
#pragma unroll
                for (int jj = 0; jj < 4; ++jj)
                    Epi[wr * 32 + m * 16 + sl * 4 + jj][col] = acc[m][n][jj] + bsn;
        }
        __syncthreads();

        // In-place per-head softmax (cols 96..191) + sidx (cols 0..95).
#pragma unroll
        for (int i = 0; i < 2; ++i) {
            const int p = t + i * 256;
            const int q = p >> 3, h = p & 7;
            const float ref = refp[qrow0 + q];
            float* lg = &Epi[q][96 + h * 12];
            float mx = -1e30f;
#pragma unroll
            for (int jj = 0; jj < 12; ++jj) mx = fmaxf(mx, lg[jj]);
            float e[12]; float s = 0.f;
#pragma unroll
            for (int jj = 0; jj < 12; ++jj) { e[jj] = expf(lg[jj] - mx); s += e[jj]; }
            const float inv = 1.f / s;
#pragma unroll
            for (int jj = 0; jj < 12; ++jj) lg[jj] = e[jj] * inv;
            float* off = &Epi[q][h * 12];
#pragma unroll
            for (int jj = 0; jj < 12; ++jj) {
                const int l = jj >> 2;
                const int T = 2048 >> l;
                float pos = ref + off[jj] / (float)T;
                pos = fminf(fmaxf(pos, 0.f), 1.f);
                off[jj] = pos * (float)(T - 1);
            }
        }
        __syncthreads();

        // Coalesced writeout: 64 x 192 f32 = 3072 float4, 12 per thread.
#pragma unroll
        for (int i = 0; i < 12; ++i) {
            const int idx = t + i * 256;
            const int q = idx / 48, c4 = idx % 48;
            const float4 o = *reinterpret_cast<const float4*>(&Epi[q][c4 * 4]);
            *reinterpret_cast<float4*>(&rows[(size_t)(qrow0 + q) * 192 + c4 * 4]) = o;
        }
    }
}

// ---------------------------------------------------------------------------
// K3: gather + lerp + weighted sum, 4x vectorized.
// One wave per query (8 heads x 8 channel-quads), 4 queries per block.
// ushort4 (8B) gathers; grid 4096 with bid&7 = batch -> XCD L2 affinity.
// ---------------------------------------------------------------------------
__global__ __launch_bounds__(256) void sample_kernel(
    const float* __restrict__ rows,            // [16384,192]  sidx | aw
    const unsigned short* __restrict__ vproj,  // [28672,128]  bf16, level-major
    unsigned short* __restrict__ out_mid)      // [16384,256]  bf16
{
    const int bid = blockIdx.x;                // 0..4095
    const int b = bid & 7;
    const int q0 = (b << 11) + ((bid >> 3) << 2);   // 4 queries/block
    const int t = threadIdx.x;
    const int w = t >> 6, lane = t & 63;
    const int h = lane >> 3, c4 = lane & 7;    // channel = c4*4 .. +3

    __shared__ float srow[4][192];
    {
        const float* src = rows + (size_t)q0 * 192;
#pragma unroll
        for (int i = 0; i < 3; ++i) {
            const int idx = t + i * 256;       // 0..767, coalesced
            srow[idx / 192][idx % 192] = src[idx];
        }
    }
    __syncthreads();

    float acc0 = 0.f, acc1 = 0.f, acc2 = 0.f, acc3 = 0.f;
#pragma unroll
    for (int l = 0; l < 3; ++l) {
        const int T = 2048 >> l;
        const int loff = (l == 0) ? 0 : ((l == 1) ? 16384 : 24576);
#pragma unroll
        for (int p = 0; p < 4; ++p) {
            const int j = h * 12 + l * 4 + p;
            const float wgt  = srow[w][96 + j];
            const float sidx = srow[w][j];
            int ifl = (int)sidx;
            ifl = min(max(ifl, 0), T - 2);
            const float wce = sidx - (float)ifl;
            const size_t base = ((size_t)(loff + b * T + ifl)) * 128 + p * 32 + c4 * 4;
            const ushort4 vf = *reinterpret_cast<const ushort4*>(&vproj[base]);
            const ushort4 vc = *reinterpret_cast<const ushort4*>(&vproj[base + 128]);
            const float f0 = bf2f(vf.x), f1 = bf2f(vf.y), f2 = bf2f(vf.z), f3 = bf2f(vf.w);
            const float g0 = bf2f(vc.x), g1 = bf2f(vc.y), g2 = bf2f(vc.z), g3 = bf2f(vc.w);
            acc0 += wgt * (f0 + wce * (g0 - f0));
            acc1 += wgt * (f1 + wce * (g1 - f1));
            acc2 += wgt * (f2 + wce * (g2 - f2));
            acc3 += wgt * (f3 + wce * (g3 - f3));
        }
    }
    ushort4 o;
    o.x = f2bf(acc0); o.y = f2bf(acc1); o.z = f2bf(acc2); o.w = f2bf(acc3);
    *reinterpret_cast<ushort4*>(&out_mid[(size_t)(q0 + w) * 256 + h * 32 + c4 * 4]) = o;
}

// ---------------------------------------------------------------------------
// K4: output projection, XCD-batch-aligned.
// 1D grid 256: b = bid&7, row-tile = (bid>>3)&15, col-tile = bid>>7.
// omid for batch b was produced on XCD b -> L2-resident reads.
// ---------------------------------------------------------------------------
__global__ __launch_bounds__(256) void outproj_kernel(
    const unsigned short* __restrict__ omid,   // [16384,256] bf16
    const unsigned short* __restrict__ wos,    // pre-swizzled [8][4][256][8]
    const float* __restrict__ bo,
    float* __restrict__ out)
{
    __shared__ unsigned short Asub[4][128][8];  // 8 KB
    __shared__ unsigned short Bsub[4][128][8];  // 8 KB
    __shared__ float Epi2[32][132];             // 16.5 KB

    const int t = threadIdx.x;
    const int bid = blockIdx.x;
    const int b = bid & 7;
    const int row0 = b * 2048 + ((bid >> 3) & 15) * 128;
    const int col0 = (bid >> 7) * 128;

    const int ar = t >> 1, ah = t & 1;
    const int w = t >> 6, lane = t & 63;
    const int wr = w >> 1, wc = w & 1;
    const int fr = lane & 15, sl = lane >> 4;

    f32x4 acc[4][4];
#pragma unroll
    for (int m = 0; m < 4; ++m)
#pragma unroll
        for (int n = 0; n < 4; ++n) acc[m][n] = (f32x4){0.f, 0.f, 0.f, 0.f};

    for (int k0t = 0; k0t < 8; ++k0t) {
        const int k0 = k0t * 32;
#pragma unroll
        for (int q = 0; q < 2; ++q) {           // stage A: 16B copies (bf16 src)
            const int slot = ah * 2 + q;
            *reinterpret_cast<u16x8*>(&Asub[slot][ar][0]) =
                *reinterpret_cast<const u16x8*>(&omid[(size_t)(row0 + ar) * 256 + k0 + slot * 8]);
        }
        {                                        // stage B: 16B copies from wos
            const u16x8* src = reinterpret_cast<const u16x8*>(wos + (size_t)k0t * 8192);
#pragma unroll
            for (int i = 0; i < 2; ++i) {
                const int ch = t + i * 256;      // 0..511
                *reinterpret_cast<u16x8*>(&Bsub[ch >> 7][ch & 127][0]) =
                    src[(ch >> 7) * 256 + col0 + (ch & 127)];
            }
        }
        __syncthreads();

        bf16x8 bfrag[4];
#pragma unroll
        for (int n = 0; n < 4; ++n)
            bfrag[n] = *reinterpret_cast<bf16x8*>(&Bsub[sl][wc * 64 + n * 16 + fr][0]);
#pragma unroll
        for (int m = 0; m < 4; ++m) {
            bf16x8 afrag = *reinterpret_cast<bf16x8*>(&Asub[sl][wr * 64 + m * 16 + fr][0]);
#pragma unroll
            for (int n = 0; n < 4; ++n)
                acc[m][n] = __builtin_amdgcn_mfma_f32_16x16x32_bf16(afrag, bfrag[n], acc[m][n], 0, 0, 0);
        }
        __syncthreads();
    }

    float bs[4];
#pragma unroll
    for (int n = 0; n < 4; ++n) bs[n] = bo[col0 + wc * 64 + n * 16 + fr];

#pragma unroll
    for (int m = 0; m < 4; ++m) {
#pragma unroll
        for (int n = 0; n < 4; ++n)
#pragma unroll
            for (int j = 0; j < 4; ++j)
                Epi2[wr * 16 + sl * 4 + j][wc * 64 + n * 16 + fr] = acc[m][n][j] + bs[n];
        __syncthreads();
#pragma unroll
        for (int i = 0; i < 4; ++i) {            // 1024 float4 chunks, 4/thread
            const int idx = t + i * 256;
            const int rb = idx >> 5, c4 = idx & 31;
            const int grow = row0 + m * 16 + (rb >> 4) * 64 + (rb & 15);
            const float4 o = *reinterpret_cast<const float4*>(&Epi2[rb][c4 * 4]);
            *reinterpret_cast<float4*>(&out[(size_t)grow * 256 + col0 + c4 * 4]) = o;
        }
        __syncthreads();
    }
}

extern "C" void kernel_launch(void* const* d_in, const int* in_sizes, int n_in,
                              void* d_out, int out_size, void* d_ws, size_t ws_size,
                              hipStream_t stream) {
    (void)in_sizes; (void)n_in; (void)out_size; (void)ws_size;
    const float* query = (const float*)d_in[0];
    const float* refp  = (const float*)d_in[1];
    const float* v0    = (const float*)d_in[2];
    const float* v1    = (const float*)d_in[3];
    const float* v2    = (const float*)d_in[4];
    const float* Woff  = (const float*)d_in[5];
    const float* boff  = (const float*)d_in[6];
    const float* Waw   = (const float*)d_in[7];
    const float* baw   = (const float*)d_in[8];
    const float* Wv    = (const float*)d_in[9];
    const float* bv    = (const float*)d_in[10];
    const float* Wo    = (const float*)d_in[11];
    const float* bo    = (const float*)d_in[12];
    float* out = (float*)d_out;

    char* ws = (char*)d_ws;
    unsigned short* vproj = (unsigned short*)(ws);             // 7,340,032 B
    float*          rows  = (float*)(ws + 7340032);            // 12,582,912 B
    unsigned short* omid  = (unsigned short*)(ws + 19922944);  // 8,388,608 B
    unsigned short* wcat  = (unsigned short*)(ws + 28311552);  //    98,304 B
    unsigned short* wvs   = (unsigned short*)(ws + 28409856);  //    65,536 B
    unsigned short* wos   = (unsigned short*)(ws + 28475392);  //   131,072 B
    float*          bcat  = (float*)(ws + 28606464);           //       768 B

    // K0: weight pre-swizzle (bf16, staging layout)
    swizzle_w_kernel<<<576, 256, 0, stream>>>(Woff, Waw, boff, baw, Wv, Wo,
                                              wcat, wvs, wos, bcat);

    // K12: merged vproj + logits/softmax/sidx, XCD-batch-aligned
    fused_k12_kernel<<<480, 256, 0, stream>>>(v0, v1, v2, wvs, bv, vproj,
                                              query, wcat, bcat, refp, rows);

    // K3: gather + lerp + weighted sum (vectorized, XCD-aligned)
    sample_kernel<<<4096, 256, 0, stream>>>(rows, vproj, omid);

    // K4: output projection (XCD-aligned)
    outproj_kernel<<<256, 256, 0, stream>>>(omid, wos, bo, out);
}